// Round 1
// baseline (338.198 us; speedup 1.0000x reference)
//
#include <hip/hip_runtime.h>
#include <stdint.h>

// B=512, T=256, N_EMBED=384, HEAD_SIZE=64
// ws layout (bytes):
//   [0, 147456)            Wt2  bf16 [12 kc][192 n][32 kk]  (n: 0..63=K, 64..127=Q(scaled), 128..191=V)
//   [147456, +16MiB)       Kd   bf16 [B*T][64]
//   [.., +16MiB)           Qd   bf16 [B*T][64]   (pre-scaled by 0.125*log2e)
//   [.., +16MiB)           Vd   bf16 [B*T][64]
// total ~48.2 MB of d_ws

typedef short s16x8 __attribute__((ext_vector_type(8)));
typedef float f32x4 __attribute__((ext_vector_type(4)));

#define LOG2E_OVER_8 0.18033688011112042f

__device__ inline short f2bf(float f) {
  union { float f; uint32_t u; } v; v.f = f;
  uint32_t r = (v.u + 0x7fffu + ((v.u >> 16) & 1u)) >> 16;  // RNE
  return (short)r;
}

// ---- Kernel 0: W fp32 [384][64] x3 -> bf16 Wt2[kc][n][kk], fold softmax scale into Wq
__global__ __launch_bounds__(256) void prep_w(const float* __restrict__ Wk,
                                              const float* __restrict__ Wq,
                                              const float* __restrict__ Wv,
                                              short* __restrict__ Wt2) {
  int idx = blockIdx.x * 256 + threadIdx.x;  // 0..73727
  int kk = idx & 31;
  int n = (idx >> 5) % 192;
  int kc = idx / (32 * 192);
  int col = n & 63;
  int w = n >> 6;
  const float* W = (w == 0) ? Wk : (w == 1) ? Wq : Wv;
  float v = W[(kc * 32 + kk) * 64 + col];
  if (w == 1) v *= LOG2E_OVER_8;
  Wt2[idx] = f2bf(v);
}

// ---- Kernel 1: fused QKV projection. Block = 128 rows x 192 cols (K|Q|V), K-loop 12x32.
__global__ __launch_bounds__(256) void qkv_proj(const float* __restrict__ x,
                                                const short* __restrict__ Wt2,
                                                short* __restrict__ Kd,
                                                short* __restrict__ Qd,
                                                short* __restrict__ Vd) {
  __shared__ short Xs[128 * 56];   // stride 56 bf16 (112 B, 16B-aligned, full LDS bank spread)
  __shared__ short Ws[192 * 32];   // [n][kk] chunk, contiguous
  const int tid = threadIdx.x;
  const int wave = tid >> 6;
  const int lane = tid & 63;
  const int l15 = lane & 15;
  const int quad = lane >> 4;
  const long m0 = (long)blockIdx.x * 128;

  f32x4 acc[2][12];
#pragma unroll
  for (int mt = 0; mt < 2; ++mt)
#pragma unroll
    for (int n = 0; n < 12; ++n) acc[mt][n] = (f32x4)0.0f;

  const int xrow = tid >> 1;
  const int xcb = (tid & 1) * 16;
  const float* xp0 = x + (m0 + xrow) * 384 + xcb;
  const short* wp0 = Wt2 + tid * 24;
  short* xs = &Xs[xrow * 56 + xcb];
  short* wsp = &Ws[tid * 24];

  for (int kc = 0; kc < 12; ++kc) {
    // stage X (fp32 -> bf16)
    const float* xp = xp0 + kc * 32;
    f32x4 a0 = *(const f32x4*)(xp);
    f32x4 a1 = *(const f32x4*)(xp + 4);
    f32x4 a2 = *(const f32x4*)(xp + 8);
    f32x4 a3 = *(const f32x4*)(xp + 12);
    // stage W (already bf16)
    const short* wp = wp0 + kc * 6144;
    s16x8 w0 = *(const s16x8*)(wp);
    s16x8 w1 = *(const s16x8*)(wp + 8);
    s16x8 w2 = *(const s16x8*)(wp + 16);

    s16x8 v0, v1;
    v0[0] = f2bf(a0[0]); v0[1] = f2bf(a0[1]); v0[2] = f2bf(a0[2]); v0[3] = f2bf(a0[3]);
    v0[4] = f2bf(a1[0]); v0[5] = f2bf(a1[1]); v0[6] = f2bf(a1[2]); v0[7] = f2bf(a1[3]);
    v1[0] = f2bf(a2[0]); v1[1] = f2bf(a2[1]); v1[2] = f2bf(a2[2]); v1[3] = f2bf(a2[3]);
    v1[4] = f2bf(a3[0]); v1[5] = f2bf(a3[1]); v1[6] = f2bf(a3[2]); v1[7] = f2bf(a3[3]);
    *(s16x8*)xs = v0;
    *(s16x8*)(xs + 8) = v1;
    *(s16x8*)wsp = w0;
    *(s16x8*)(wsp + 8) = w1;
    *(s16x8*)(wsp + 16) = w2;
    __syncthreads();

    s16x8 af0 = *(const s16x8*)&Xs[(wave * 32 + l15) * 56 + quad * 8];
    s16x8 af1 = *(const s16x8*)&Xs[(wave * 32 + 16 + l15) * 56 + quad * 8];
#pragma unroll
    for (int n = 0; n < 12; ++n) {
      s16x8 bf = *(const s16x8*)&Ws[(n * 16 + l15) * 32 + quad * 8];
      acc[0][n] = __builtin_amdgcn_mfma_f32_16x16x32_bf16(af0, bf, acc[0][n], 0, 0, 0);
      acc[1][n] = __builtin_amdgcn_mfma_f32_16x16x32_bf16(af1, bf, acc[1][n], 0, 0, 0);
    }
    __syncthreads();
  }

  // epilogue: C layout col=l15, row=quad*4+r
#pragma unroll
  for (int mt = 0; mt < 2; ++mt) {
    const long rbase = m0 + wave * 32 + mt * 16 + quad * 4;
#pragma unroll
    for (int n = 0; n < 12; ++n) {
      short* dst = (n < 4) ? Kd : (n < 8) ? Qd : Vd;
      const int col = (n & 3) * 16 + l15;
#pragma unroll
      for (int r = 0; r < 4; ++r) {
        dst[(rbase + r) * 64 + col] = f2bf(acc[mt][n][r]);
      }
    }
  }
}

// ---- Kernel 2: causal attention, one block per (batch, 64-row q-tile), chunked over s (64).
__global__ __launch_bounds__(256) void attn_head(const short* __restrict__ Kd,
                                                 const short* __restrict__ Qd,
                                                 const short* __restrict__ Vd,
                                                 float* __restrict__ out) {
  __shared__ short Ks[64 * 72];     // [s][h], stride 72
  __shared__ short Vt[64 * 72];     // [h][s], stride 72 (transposed at load)
  __shared__ short Ps[4][16 * 72];  // per-wave P strip [t][s], stride 72
  const int tid = threadIdx.x;
  const int wave = tid >> 6;
  const int lane = tid & 63;
  const int l15 = lane & 15;
  const int quad = lane >> 4;
  const int b = blockIdx.x >> 2;
  const int qt = blockIdx.x & 3;
  const short* Kb = Kd + (long)b * (256 * 64);
  const short* Vb = Vd + (long)b * (256 * 64);
  const short* Qb = Qd + (long)b * (256 * 64);

  // Q fragments for this wave's 16 rows (A-layout: m=l15, k=quad*8+j), reused all chunks
  const int qrow = qt * 64 + wave * 16 + l15;
  s16x8 qf0 = *(const s16x8*)&Qb[qrow * 64 + quad * 8];
  s16x8 qf1 = *(const s16x8*)&Qb[qrow * 64 + 32 + quad * 8];

  f32x4 Oacc[4];
#pragma unroll
  for (int n = 0; n < 4; ++n) Oacc[n] = (f32x4)0.0f;
  float mrow[4] = {-1e30f, -1e30f, -1e30f, -1e30f};
  float lrow[4] = {0.f, 0.f, 0.f, 0.f};

  const int s_row = tid >> 2;       // 0..63
  const int hseg = (tid & 3) * 16;  // 0,16,32,48

  for (int c = 0; c <= qt; ++c) {
    // stage K chunk row-major; V chunk transposed
    const short* kp = Kb + (c * 64 + s_row) * 64 + hseg;
    s16x8 k0 = *(const s16x8*)kp;
    s16x8 k1 = *(const s16x8*)(kp + 8);
    const short* vp = Vb + (c * 64 + s_row) * 64 + hseg;
    s16x8 u0 = *(const s16x8*)vp;
    s16x8 u1 = *(const s16x8*)(vp + 8);
    *(s16x8*)&Ks[s_row * 72 + hseg] = k0;
    *(s16x8*)&Ks[s_row * 72 + hseg + 8] = k1;
#pragma unroll
    for (int i = 0; i < 8; ++i) Vt[(hseg + i) * 72 + s_row] = u0[i];
#pragma unroll
    for (int i = 0; i < 8; ++i) Vt[(hseg + 8 + i) * 72 + s_row] = u1[i];
    __syncthreads();

    // S = Q' K^T (already in log2 units); B-frag k=h from K rows
    f32x4 S[4];
#pragma unroll
    for (int n = 0; n < 4; ++n) {
      s16x8 kf0 = *(const s16x8*)&Ks[(n * 16 + l15) * 72 + quad * 8];
      s16x8 kf1 = *(const s16x8*)&Ks[(n * 16 + l15) * 72 + 32 + quad * 8];
      f32x4 z = (f32x4)0.0f;
      z = __builtin_amdgcn_mfma_f32_16x16x32_bf16(qf0, kf0, z, 0, 0, 0);
      z = __builtin_amdgcn_mfma_f32_16x16x32_bf16(qf1, kf1, z, 0, 0, 0);
      S[n] = z;
    }
    if (c == qt) {  // diagonal chunk: mask s_loc > q_loc
#pragma unroll
      for (int n = 0; n < 4; ++n) {
        int s_loc = n * 16 + l15;
#pragma unroll
        for (int r = 0; r < 4; ++r) {
          int q_loc = wave * 16 + quad * 4 + r;
          if (s_loc > q_loc) S[n][r] = -1e30f;
        }
      }
    }

    // online softmax (base-2). Row r lives in the 16 lanes of this quad.
    float alpha[4];
#pragma unroll
    for (int r = 0; r < 4; ++r) {
      float mx = fmaxf(fmaxf(S[0][r], S[1][r]), fmaxf(S[2][r], S[3][r]));
      mx = fmaxf(mx, __shfl_xor(mx, 1));
      mx = fmaxf(mx, __shfl_xor(mx, 2));
      mx = fmaxf(mx, __shfl_xor(mx, 4));
      mx = fmaxf(mx, __shfl_xor(mx, 8));
      float mnew = fmaxf(mrow[r], mx);
      alpha[r] = __builtin_amdgcn_exp2f(mrow[r] - mnew);
      mrow[r] = mnew;
    }
    float rs[4] = {0.f, 0.f, 0.f, 0.f};
#pragma unroll
    for (int n = 0; n < 4; ++n) {
#pragma unroll
      for (int r = 0; r < 4; ++r) {
        float p = __builtin_amdgcn_exp2f(S[n][r] - mrow[r]);  // masked -> exp2(-huge) = 0
        rs[r] += p;
        Ps[wave][(quad * 4 + r) * 72 + n * 16 + l15] = f2bf(p);
      }
    }
#pragma unroll
    for (int r = 0; r < 4; ++r) {
      float s = rs[r];
      s += __shfl_xor(s, 1);
      s += __shfl_xor(s, 2);
      s += __shfl_xor(s, 4);
      s += __shfl_xor(s, 8);
      lrow[r] = lrow[r] * alpha[r] + s;
#pragma unroll
      for (int n = 0; n < 4; ++n) Oacc[n][r] *= alpha[r];
    }
    // P strip is wave-private: drain DS writes before re-reading (no barrier needed)
    asm volatile("s_waitcnt lgkmcnt(0)" ::: "memory");

    // O += P V ; A-frag from P strip (m=l15,k=s), B-frag from Vt rows (contiguous s)
    s16x8 pf0 = *(const s16x8*)&Ps[wave][l15 * 72 + quad * 8];
    s16x8 pf1 = *(const s16x8*)&Ps[wave][l15 * 72 + 32 + quad * 8];
#pragma unroll
    for (int n = 0; n < 4; ++n) {
      s16x8 vf0 = *(const s16x8*)&Vt[(n * 16 + l15) * 72 + quad * 8];
      s16x8 vf1 = *(const s16x8*)&Vt[(n * 16 + l15) * 72 + 32 + quad * 8];
      Oacc[n] = __builtin_amdgcn_mfma_f32_16x16x32_bf16(pf0, vf0, Oacc[n], 0, 0, 0);
      Oacc[n] = __builtin_amdgcn_mfma_f32_16x16x32_bf16(pf1, vf1, Oacc[n], 0, 0, 0);
    }
    __syncthreads();  // protect Ks/Vt before next chunk's staging
  }

  float inv[4];
#pragma unroll
  for (int r = 0; r < 4; ++r) inv[r] = 1.0f / lrow[r];
  float* ob = out + ((long)b * 256 + qt * 64 + wave * 16 + quad * 4) * 64;
#pragma unroll
  for (int n = 0; n < 4; ++n)
#pragma unroll
    for (int r = 0; r < 4; ++r)
      ob[r * 64 + n * 16 + l15] = Oacc[n][r] * inv[r];
}

extern "C" void kernel_launch(void* const* d_in, const int* in_sizes, int n_in,
                              void* d_out, int out_size, void* d_ws, size_t ws_size,
                              hipStream_t stream) {
  const float* x = (const float*)d_in[0];
  const float* Wk = (const float*)d_in[1];
  const float* Wq = (const float*)d_in[2];
  const float* Wv = (const float*)d_in[3];
  float* out = (float*)d_out;
  char* ws = (char*)d_ws;
  short* Wt2 = (short*)ws;                                 // 147456 B
  short* Kd = (short*)(ws + 147456);                       // 16 MiB
  short* Qd = (short*)(ws + 147456 + 16777216);            // 16 MiB
  short* Vd = (short*)(ws + 147456 + 2 * 16777216);        // 16 MiB

  prep_w<<<288, 256, 0, stream>>>(Wk, Wq, Wv, Wt2);
  qkv_proj<<<1024, 256, 0, stream>>>(x, Wt2, Kd, Qd, Vd);
  attn_head<<<2048, 256, 0, stream>>>(Kd, Qd, Vd, out);
}